// Round 1
// baseline (291.911 us; speedup 1.0000x reference)
//
#include <hip/hip_runtime.h>

#define N_NODES 50000
#define N_EDGES 600000
#define D 128
#define N_RELS 460

// workspace layout (element offsets, all 4-byte elements)
enum : int {
    OFF_W       = 0,         //   384 floats  (w = fc1^T @ fc2^T, split w1|w2|w3)
    OFF_S1      = 384,       // 50000 floats  (h . w1 per node)
    OFF_S2      = 50384,     // 50000 floats  (h . w2 per node)
    OFF_S3      = 100384,    //   460 floats  (rel . w3 per relation) + pad
    OFF_COUNTS  = 100864,    // 50000 ints    (in-degree histogram)
    OFF_CURSOR  = 150864,    // 50000 ints    (CSR fill cursors)
    OFF_OFFSETS = 200864,    // 50001 ints    (CSR row offsets) + pad
    OFF_BSUMS   = 250880,    //   256 ints    (scan block sums)
    OFF_SRCS    = 251136,    // 600000 ints   (CSR-sorted edge src)
    OFF_EXS     = 851136,    // 600000 floats (CSR-sorted exp(e))
};                           // total 1451136 elems = 5.54 MiB

// ---------- K0: w[j] = sum_k fc2[k] * fc1[k][j],  j in [0, 3D) ----------
__global__ void k_w(const float* __restrict__ fc1, const float* __restrict__ fc2,
                    float* __restrict__ w) {
    int j = threadIdx.x;             // 384 threads, 1 block
    if (j >= 3 * D) return;
    float acc = 0.f;
    for (int k = 0; k < D; ++k) acc += fc2[k] * fc1[k * 3 * D + j];
    w[j] = acc;
}

// ---------- K1: per-node s1,s2 and per-rel s3 (one wave per row) ----------
__global__ void k_scores(const float* __restrict__ h, const float* __restrict__ emb_rel,
                         const float* __restrict__ w,
                         float* __restrict__ s1, float* __restrict__ s2,
                         float* __restrict__ s3) {
    int wid  = (blockIdx.x * blockDim.x + threadIdx.x) >> 6;
    int lane = threadIdx.x & 63;
    if (wid < N_NODES) {
        float2 hv = ((const float2*)(h + (size_t)wid * D))[lane];
        float2 w1 = ((const float2*)(w))[lane];
        float2 w2 = ((const float2*)(w + D))[lane];
        float a1 = hv.x * w1.x + hv.y * w1.y;
        float a2 = hv.x * w2.x + hv.y * w2.y;
        #pragma unroll
        for (int o = 32; o; o >>= 1) { a1 += __shfl_xor(a1, o); a2 += __shfl_xor(a2, o); }
        if (lane == 0) { s1[wid] = a1; s2[wid] = a2; }
    } else if (wid < N_NODES + N_RELS) {
        int r = wid - N_NODES;
        float2 rv = ((const float2*)(emb_rel + (size_t)r * D))[lane];
        float2 w3 = ((const float2*)(w + 2 * D))[lane];
        float a3 = rv.x * w3.x + rv.y * w3.y;
        #pragma unroll
        for (int o = 32; o; o >>= 1) a3 += __shfl_xor(a3, o);
        if (lane == 0) s3[r] = a3;
    }
}

// ---------- K2: in-degree histogram ----------
__global__ void k_count(const int* __restrict__ dst, int* __restrict__ counts) {
    int e = blockIdx.x * blockDim.x + threadIdx.x;
    if (e < N_EDGES) atomicAdd(&counts[dst[e]], 1);
}

// ---------- scan: counts[0..N) -> offsets[0..N] (exclusive) ----------
__global__ void k_scan1(const int* __restrict__ counts, int* __restrict__ offsets,
                        int* __restrict__ bsums) {
    __shared__ int s[256];
    int i = blockIdx.x * 256 + threadIdx.x;
    int v = (i < N_NODES) ? counts[i] : 0;
    s[threadIdx.x] = v;
    __syncthreads();
    for (int off = 1; off < 256; off <<= 1) {
        int t = (threadIdx.x >= off) ? s[threadIdx.x - off] : 0;
        __syncthreads();
        s[threadIdx.x] += t;
        __syncthreads();
    }
    if (i < N_NODES) offsets[i + 1] = s[threadIdx.x];   // inclusive within block
    if (blockIdx.x == 0 && threadIdx.x == 0) offsets[0] = 0;
    if (threadIdx.x == 255) bsums[blockIdx.x] = s[255];
}

__global__ void k_scan2(int* __restrict__ bsums, int nb) {
    __shared__ int s[256];
    int t = threadIdx.x;
    s[t] = (t < nb) ? bsums[t] : 0;
    __syncthreads();
    for (int off = 1; off < 256; off <<= 1) {
        int v = (t >= off) ? s[t - off] : 0;
        __syncthreads();
        s[t] += v;
        __syncthreads();
    }
    if (t < nb) bsums[t] = s[t];                        // inclusive scan of block sums
}

__global__ void k_scan3(int* __restrict__ offsets, const int* __restrict__ bsums) {
    int i = blockIdx.x * 256 + threadIdx.x;
    if (i < N_NODES && blockIdx.x > 0) offsets[i + 1] += bsums[blockIdx.x - 1];
}

// ---------- K3: compute exp(leaky(e)) and place edge into CSR slot ----------
__global__ void k_scatter(const int* __restrict__ src, const int* __restrict__ dst,
                          const int* __restrict__ typ,
                          const float* __restrict__ s1, const float* __restrict__ s2,
                          const float* __restrict__ s3,
                          const int* __restrict__ offsets, int* __restrict__ cursor,
                          int* __restrict__ srcs, float* __restrict__ exs) {
    int e = blockIdx.x * blockDim.x + threadIdx.x;
    if (e >= N_EDGES) return;
    int d = dst[e];
    int sidx = src[e];
    float x = s1[sidx] + s2[d] + s3[typ[e]];
    float lv = (x > 0.f) ? x : 0.01f * x;               // leaky_relu slope 0.01
    float ex = __expf(lv);                              // no max-sub needed: |x| <~ 3.5
    int slot = offsets[d] + atomicAdd(&cursor[d], 1);
    srcs[slot] = sidx;
    exs[slot] = ex;
}

// ---------- K5: out = h @ loop_weight  (fp32, W in LDS, 4x8 reg blocking) ----------
__global__ __launch_bounds__(256) void k_gemm(const float* __restrict__ h,
                                              const float* __restrict__ W,
                                              float* __restrict__ out) {
    __shared__ float Ws[D * D];                          // 64 KiB
    int t = threadIdx.x;
    for (int i = t; i < (D * D) / 4; i += 256)
        ((float4*)Ws)[i] = ((const float4*)W)[i];
    __syncthreads();

    int base = blockIdx.x * 64;
    int ng = t >> 4;                 // 16 node groups x 4 nodes
    int cg = (t & 15) << 3;          // 16 col groups  x 8 cols
    int n0 = base + ng * 4;

    float acc[4][8];
    #pragma unroll
    for (int i = 0; i < 4; ++i)
        #pragma unroll
        for (int q = 0; q < 8; ++q) acc[i][q] = 0.f;

    for (int k = 0; k < D; k += 4) {
        float hv[4][4];
        #pragma unroll
        for (int i = 0; i < 4; ++i) {
            int n = n0 + i;
            float4 v = (n < N_NODES) ? *((const float4*)(h + (size_t)n * D + k))
                                     : make_float4(0.f, 0.f, 0.f, 0.f);
            hv[i][0] = v.x; hv[i][1] = v.y; hv[i][2] = v.z; hv[i][3] = v.w;
        }
        #pragma unroll
        for (int m = 0; m < 4; ++m) {
            const float* wr = Ws + (k + m) * D + cg;
            float4 w0 = *((const float4*)wr);
            float4 w1 = *((const float4*)(wr + 4));
            float wv[8] = {w0.x, w0.y, w0.z, w0.w, w1.x, w1.y, w1.z, w1.w};
            #pragma unroll
            for (int i = 0; i < 4; ++i)
                #pragma unroll
                for (int q = 0; q < 8; ++q)
                    acc[i][q] += hv[i][m] * wv[q];
        }
    }
    #pragma unroll
    for (int i = 0; i < 4; ++i) {
        int n = n0 + i;
        if (n < N_NODES) {
            float4 o0 = {acc[i][0], acc[i][1], acc[i][2], acc[i][3]};
            float4 o1 = {acc[i][4], acc[i][5], acc[i][6], acc[i][7]};
            *((float4*)(out + (size_t)n * D + cg))     = o0;
            *((float4*)(out + (size_t)n * D + cg + 4)) = o1;
        }
    }
}

// ---------- K4: per-node softmax-normalize + weighted gather (one wave/node) ----------
__global__ void k_gather(const float* __restrict__ h, const int* __restrict__ offsets,
                         const int* __restrict__ srcs, const float* __restrict__ exs,
                         float* __restrict__ out) {
    int n    = (blockIdx.x * blockDim.x + threadIdx.x) >> 6;
    int lane = threadIdx.x & 63;
    if (n >= N_NODES) return;
    int beg = offsets[n], end = offsets[n + 1];
    if (beg == end) return;                              // deg 0: out = h@W only

    float den = 0.f;
    for (int i = beg + lane; i < end; i += 64) den += exs[i];
    #pragma unroll
    for (int o = 32; o; o >>= 1) den += __shfl_xor(den, o);
    float inv = 1.f / den;

    float2 acc = {0.f, 0.f};
    for (int cb = beg; cb < end; cb += 64) {
        int i = cb + lane;
        int   msrc = (i < end) ? srcs[i] : 0;
        float mco  = (i < end) ? exs[i] * inv : 0.f;
        int cnt = min(64, end - cb);
        for (int j = 0; j < cnt; ++j) {
            int   s = __shfl(msrc, j);
            float c = __shfl(mco, j);
            float2 hv = ((const float2*)(h + (size_t)s * D))[lane];
            acc.x += c * hv.x;
            acc.y += c * hv.y;
        }
    }
    float2* op = (float2*)(out + (size_t)n * D);
    float2 cur = op[lane];
    op[lane] = make_float2(cur.x + acc.x, cur.y + acc.y);
}

extern "C" void kernel_launch(void* const* d_in, const int* in_sizes, int n_in,
                              void* d_out, int out_size, void* d_ws, size_t ws_size,
                              hipStream_t stream) {
    const float* h       = (const float*)d_in[0];
    const float* emb_rel = (const float*)d_in[1];
    const float* fc1     = (const float*)d_in[2];   // [D, 3D]
    const float* fc2     = (const float*)d_in[3];   // [1, D]
    const float* loopw   = (const float*)d_in[4];   // [D, D]
    const int*   esrc    = (const int*)d_in[5];
    const int*   edst    = (const int*)d_in[6];
    const int*   etyp    = (const int*)d_in[7];
    float* out = (float*)d_out;
    float* ws  = (float*)d_ws;

    float* w       = ws + OFF_W;
    float* s1      = ws + OFF_S1;
    float* s2      = ws + OFF_S2;
    float* s3      = ws + OFF_S3;
    int*   counts  = (int*)(ws + OFF_COUNTS);
    int*   cursor  = (int*)(ws + OFF_CURSOR);
    int*   offsets = (int*)(ws + OFF_OFFSETS);
    int*   bsums   = (int*)(ws + OFF_BSUMS);
    int*   srcs    = (int*)(ws + OFF_SRCS);
    float* exs     = ws + OFF_EXS;

    // zero counts + cursor (contiguous 100000 ints); ws is poisoned each call
    hipMemsetAsync(counts, 0, 100000 * sizeof(int), stream);

    k_w<<<1, 384, 0, stream>>>(fc1, fc2, w);

    int score_blocks = (N_NODES + N_RELS + 3) / 4;       // 4 waves/block
    k_scores<<<score_blocks, 256, 0, stream>>>(h, emb_rel, w, s1, s2, s3);

    int edge_blocks = (N_EDGES + 255) / 256;
    k_count<<<edge_blocks, 256, 0, stream>>>(edst, counts);

    int scan_blocks = (N_NODES + 255) / 256;             // 196
    k_scan1<<<scan_blocks, 256, 0, stream>>>(counts, offsets, bsums);
    k_scan2<<<1, 256, 0, stream>>>(bsums, scan_blocks);
    k_scan3<<<scan_blocks, 256, 0, stream>>>(offsets, bsums);

    k_scatter<<<edge_blocks, 256, 0, stream>>>(esrc, edst, etyp, s1, s2, s3,
                                               offsets, cursor, srcs, exs);

    k_gemm<<<(N_NODES + 63) / 64, 256, 0, stream>>>(h, loopw, out);

    int gather_blocks = (N_NODES + 3) / 4;               // 4 waves/block
    k_gather<<<gather_blocks, 256, 0, stream>>>(h, offsets, srcs, exs, out);
}

// Round 2
// 225.933 us; speedup vs baseline: 1.2920x; 1.2920x over previous
//
#include <hip/hip_runtime.h>

#define N_NODES 50000
#define N_EDGES 600000
#define D 128
#define N_RELS 460

typedef unsigned short u16;
typedef __attribute__((ext_vector_type(8))) short bf16x8;   // 8 bf16 (4 VGPRs)
typedef __attribute__((ext_vector_type(4))) float f32x4;

// workspace layout (element offsets, 4-byte elements)
enum : int {
    OFF_W       = 0,         //   384 floats  (w = fc1^T @ fc2^T, split w1|w2|w3)
    OFF_S1      = 384,       // 50000 floats
    OFF_S2      = 50384,     // 50000 floats
    OFF_S3      = 100384,    //   460 floats + pad
    OFF_COUNTS  = 100864,    // 50000 ints
    OFF_CURSOR  = 150864,    // 50000 ints
    OFF_OFFSETS = 200864,    // 50001 ints + pad
    OFF_BSUMS   = 250880,    //   256 ints
    OFF_SRCS    = 251136,    // 600000 ints   (CSR-sorted edge src)
    OFF_EXS     = 851136,    // 600000 floats (CSR-sorted exp(e))
    OFF_HB      = 1451136,   // 6400000 bf16 = 3200000 float slots (h in bf16)
    OFF_WT      = 4651136,   // 16384 bf16 = 8192 float slots (loop_weight^T bf16)
};                           // total 4659328 elems = 17.8 MiB

__device__ __forceinline__ u16 f2bf(float f) {
    unsigned u = __float_as_uint(f);
    unsigned r = u + 0x7FFFu + ((u >> 16) & 1u);   // RNE
    return (u16)(r >> 16);
}

// ---------- K0: w[j] = sum_k fc2[k] * fc1[k][j] ----------
__global__ void k_w(const float* __restrict__ fc1, const float* __restrict__ fc2,
                    float* __restrict__ w) {
    int j = threadIdx.x;
    if (j >= 3 * D) return;
    float acc = 0.f;
    for (int k = 0; k < D; ++k) acc += fc2[k] * fc1[k * 3 * D + j];
    w[j] = acc;
}

// ---------- cast h -> bf16 (row-major, same layout) ----------
__global__ void k_cast_h(const float* __restrict__ h, u16* __restrict__ hb) {
    int i = blockIdx.x * blockDim.x + threadIdx.x;      // 1.6M threads, 4 elems each
    float4 v = ((const float4*)h)[i];
    unsigned long long p = (unsigned long long)f2bf(v.x)
                         | ((unsigned long long)f2bf(v.y) << 16)
                         | ((unsigned long long)f2bf(v.z) << 32)
                         | ((unsigned long long)f2bf(v.w) << 48);
    ((unsigned long long*)hb)[i] = p;
}

// ---------- cast + transpose loop_weight: Wt[n][k] = W[k][n] ----------
__global__ void k_cast_w(const float* __restrict__ W, u16* __restrict__ wt) {
    int i = blockIdx.x * blockDim.x + threadIdx.x;      // 16384 threads
    int k = i >> 7, n = i & 127;
    wt[n * D + k] = f2bf(W[k * D + n]);
}

// ---------- K1: per-node s1,s2 and per-rel s3 (one wave per row) ----------
__global__ void k_scores(const float* __restrict__ h, const float* __restrict__ emb_rel,
                         const float* __restrict__ w,
                         float* __restrict__ s1, float* __restrict__ s2,
                         float* __restrict__ s3) {
    int wid  = (blockIdx.x * blockDim.x + threadIdx.x) >> 6;
    int lane = threadIdx.x & 63;
    if (wid < N_NODES) {
        float2 hv = ((const float2*)(h + (size_t)wid * D))[lane];
        float2 w1 = ((const float2*)(w))[lane];
        float2 w2 = ((const float2*)(w + D))[lane];
        float a1 = hv.x * w1.x + hv.y * w1.y;
        float a2 = hv.x * w2.x + hv.y * w2.y;
        #pragma unroll
        for (int o = 32; o; o >>= 1) { a1 += __shfl_xor(a1, o); a2 += __shfl_xor(a2, o); }
        if (lane == 0) { s1[wid] = a1; s2[wid] = a2; }
    } else if (wid < N_NODES + N_RELS) {
        int r = wid - N_NODES;
        float2 rv = ((const float2*)(emb_rel + (size_t)r * D))[lane];
        float2 w3 = ((const float2*)(w + 2 * D))[lane];
        float a3 = rv.x * w3.x + rv.y * w3.y;
        #pragma unroll
        for (int o = 32; o; o >>= 1) a3 += __shfl_xor(a3, o);
        if (lane == 0) s3[r] = a3;
    }
}

// ---------- K2: in-degree histogram ----------
__global__ void k_count(const int* __restrict__ dst, int* __restrict__ counts) {
    int e = blockIdx.x * blockDim.x + threadIdx.x;
    if (e < N_EDGES) atomicAdd(&counts[dst[e]], 1);
}

// ---------- scan: counts -> offsets (exclusive) ----------
__global__ void k_scan1(const int* __restrict__ counts, int* __restrict__ offsets,
                        int* __restrict__ bsums) {
    __shared__ int s[256];
    int i = blockIdx.x * 256 + threadIdx.x;
    int v = (i < N_NODES) ? counts[i] : 0;
    s[threadIdx.x] = v;
    __syncthreads();
    for (int off = 1; off < 256; off <<= 1) {
        int t = (threadIdx.x >= off) ? s[threadIdx.x - off] : 0;
        __syncthreads();
        s[threadIdx.x] += t;
        __syncthreads();
    }
    if (i < N_NODES) offsets[i + 1] = s[threadIdx.x];
    if (blockIdx.x == 0 && threadIdx.x == 0) offsets[0] = 0;
    if (threadIdx.x == 255) bsums[blockIdx.x] = s[255];
}

__global__ void k_scan2(int* __restrict__ bsums, int nb) {
    __shared__ int s[256];
    int t = threadIdx.x;
    s[t] = (t < nb) ? bsums[t] : 0;
    __syncthreads();
    for (int off = 1; off < 256; off <<= 1) {
        int v = (t >= off) ? s[t - off] : 0;
        __syncthreads();
        s[t] += v;
        __syncthreads();
    }
    if (t < nb) bsums[t] = s[t];
}

__global__ void k_scan3(int* __restrict__ offsets, const int* __restrict__ bsums) {
    int i = blockIdx.x * 256 + threadIdx.x;
    if (i < N_NODES && blockIdx.x > 0) offsets[i + 1] += bsums[blockIdx.x - 1];
}

// ---------- K3: exp(leaky(e)) + CSR slot placement ----------
__global__ void k_scatter(const int* __restrict__ src, const int* __restrict__ dst,
                          const int* __restrict__ typ,
                          const float* __restrict__ s1, const float* __restrict__ s2,
                          const float* __restrict__ s3,
                          const int* __restrict__ offsets, int* __restrict__ cursor,
                          int* __restrict__ srcs, float* __restrict__ exs) {
    int e = blockIdx.x * blockDim.x + threadIdx.x;
    if (e >= N_EDGES) return;
    int d = dst[e];
    int sidx = src[e];
    float x = s1[sidx] + s2[d] + s3[typ[e]];
    float lv = (x > 0.f) ? x : 0.01f * x;
    float ex = __expf(lv);                 // |x| small; no max-sub needed (shift-invariant)
    int slot = offsets[d] + atomicAdd(&cursor[d], 1);
    srcs[slot] = sidx;
    exs[slot] = ex;
}

// ---------- K5: out = h @ loop_weight via bf16 MFMA ----------
// A-frag: A[m=lane&15][k=quad*8+j]; B-frag: B[k=quad*8+j][n=lane&15];
// C/D: D[m=quad*4+reg][n=lane&15]. Wt is [n][k] so B loads are contiguous.
#define WT_STRIDE 136   // bf16 elems per LDS row: 272 B -> 16B-aligned b128, bank-balanced
__global__ __launch_bounds__(256) void k_gemm_mfma(const u16* __restrict__ hb,
                                                   const u16* __restrict__ wt,
                                                   float* __restrict__ out) {
    __shared__ u16 Ws[D * WT_STRIDE];                   // 34 KiB
    int t = threadIdx.x;
    for (int i = t; i < (D * D) / 8; i += 256) {        // 2048 segs of 8 bf16
        int row = i >> 4, seg = i & 15;
        *(bf16x8*)(&Ws[row * WT_STRIDE + seg * 8]) = *(const bf16x8*)(&wt[row * D + seg * 8]);
    }
    __syncthreads();

    int wave = t >> 6, lane = t & 63;
    int quad = lane >> 4, m16 = lane & 15;
    int nbase = blockIdx.x * 64 + wave * 16;

    f32x4 acc[8];
    #pragma unroll
    for (int cg = 0; cg < 8; ++cg) acc[cg] = (f32x4){0.f, 0.f, 0.f, 0.f};

    int arow = nbase + m16;
    if (arow >= N_NODES) arow = N_NODES - 1;            // clamp; stores are guarded
    const u16* aptr = hb + (size_t)arow * D + quad * 8;

    #pragma unroll
    for (int k0 = 0; k0 < D; k0 += 32) {
        bf16x8 a = *(const bf16x8*)(aptr + k0);
        #pragma unroll
        for (int cg = 0; cg < 8; ++cg) {
            bf16x8 b = *(const bf16x8*)(&Ws[(cg * 16 + m16) * WT_STRIDE + k0 + quad * 8]);
            acc[cg] = __builtin_amdgcn_mfma_f32_16x16x32_bf16(a, b, acc[cg], 0, 0, 0);
        }
    }

    #pragma unroll
    for (int reg = 0; reg < 4; ++reg) {
        int row = nbase + quad * 4 + reg;
        if (row < N_NODES) {
            #pragma unroll
            for (int cg = 0; cg < 8; ++cg)
                out[(size_t)row * D + cg * 16 + m16] = acc[cg][reg];
        }
    }
}

// ---------- K4: per-node softmax-normalize + weighted gather (bf16 rows) ----------
__global__ void k_gather(const u16* __restrict__ hb, const int* __restrict__ offsets,
                         const int* __restrict__ srcs, const float* __restrict__ exs,
                         float* __restrict__ out) {
    int n    = (blockIdx.x * blockDim.x + threadIdx.x) >> 6;
    int lane = threadIdx.x & 63;
    if (n >= N_NODES) return;
    int beg = offsets[n], end = offsets[n + 1];
    if (beg == end) return;                              // deg 0: out = h@W only

    float den = 0.f;
    for (int i = beg + lane; i < end; i += 64) den += exs[i];
    #pragma unroll
    for (int o = 32; o; o >>= 1) den += __shfl_xor(den, o);
    float inv = 1.f / den;

    float2 acc = {0.f, 0.f};
    for (int cb = beg; cb < end; cb += 64) {
        int i = cb + lane;
        int   msrc = (i < end) ? srcs[i] : 0;
        float mco  = (i < end) ? exs[i] * inv : 0.f;
        int cnt = min(64, end - cb);
        int j = 0;
        for (; j + 1 < cnt; j += 2) {
            int   s0 = __shfl(msrc, j),     s1 = __shfl(msrc, j + 1);
            float c0 = __shfl(mco, j),      c1 = __shfl(mco, j + 1);
            unsigned u0 = ((const unsigned*)(hb + (size_t)s0 * D))[lane];
            unsigned u1 = ((const unsigned*)(hb + (size_t)s1 * D))[lane];
            acc.x += c0 * __uint_as_float(u0 << 16) + c1 * __uint_as_float(u1 << 16);
            acc.y += c0 * __uint_as_float(u0 & 0xFFFF0000u) + c1 * __uint_as_float(u1 & 0xFFFF0000u);
        }
        if (j < cnt) {
            int   s0 = __shfl(msrc, j);
            float c0 = __shfl(mco, j);
            unsigned u0 = ((const unsigned*)(hb + (size_t)s0 * D))[lane];
            acc.x += c0 * __uint_as_float(u0 << 16);
            acc.y += c0 * __uint_as_float(u0 & 0xFFFF0000u);
        }
    }
    float2* op = (float2*)(out + (size_t)n * D);
    float2 cur = op[lane];
    op[lane] = make_float2(cur.x + acc.x, cur.y + acc.y);
}

extern "C" void kernel_launch(void* const* d_in, const int* in_sizes, int n_in,
                              void* d_out, int out_size, void* d_ws, size_t ws_size,
                              hipStream_t stream) {
    const float* h       = (const float*)d_in[0];
    const float* emb_rel = (const float*)d_in[1];
    const float* fc1     = (const float*)d_in[2];   // [D, 3D]
    const float* fc2     = (const float*)d_in[3];   // [1, D]
    const float* loopw   = (const float*)d_in[4];   // [D, D]
    const int*   esrc    = (const int*)d_in[5];
    const int*   edst    = (const int*)d_in[6];
    const int*   etyp    = (const int*)d_in[7];
    float* out = (float*)d_out;
    float* ws  = (float*)d_ws;

    float* w       = ws + OFF_W;
    float* s1      = ws + OFF_S1;
    float* s2      = ws + OFF_S2;
    float* s3      = ws + OFF_S3;
    int*   counts  = (int*)(ws + OFF_COUNTS);
    int*   cursor  = (int*)(ws + OFF_CURSOR);
    int*   offsets = (int*)(ws + OFF_OFFSETS);
    int*   bsums   = (int*)(ws + OFF_BSUMS);
    int*   srcs    = (int*)(ws + OFF_SRCS);
    float* exs     = ws + OFF_EXS;
    u16*   hb      = (u16*)(ws + OFF_HB);
    u16*   wt      = (u16*)(ws + OFF_WT);

    // zero counts + cursor (contiguous 100000 ints)
    hipMemsetAsync(counts, 0, 100000 * sizeof(int), stream);

    k_w<<<1, 384, 0, stream>>>(fc1, fc2, w);
    k_cast_h<<<(N_NODES * D / 4 + 255) / 256, 256, 0, stream>>>(h, hb);   // 6250 blocks
    k_cast_w<<<(D * D + 255) / 256, 256, 0, stream>>>(loopw, wt);

    int score_blocks = (N_NODES + N_RELS + 3) / 4;
    k_scores<<<score_blocks, 256, 0, stream>>>(h, emb_rel, w, s1, s2, s3);

    int edge_blocks = (N_EDGES + 255) / 256;
    k_count<<<edge_blocks, 256, 0, stream>>>(edst, counts);

    int scan_blocks = (N_NODES + 255) / 256;             // 196
    k_scan1<<<scan_blocks, 256, 0, stream>>>(counts, offsets, bsums);
    k_scan2<<<1, 256, 0, stream>>>(bsums, scan_blocks);
    k_scan3<<<scan_blocks, 256, 0, stream>>>(offsets, bsums);

    k_scatter<<<edge_blocks, 256, 0, stream>>>(esrc, edst, etyp, s1, s2, s3,
                                               offsets, cursor, srcs, exs);

    k_gemm_mfma<<<(N_NODES + 63) / 64, 256, 0, stream>>>(hb, wt, out);

    int gather_blocks = (N_NODES + 3) / 4;
    k_gather<<<gather_blocks, 256, 0, stream>>>(hb, offsets, srcs, exs, out);
}

// Round 3
// 218.449 us; speedup vs baseline: 1.3363x; 1.0343x over previous
//
#include <hip/hip_runtime.h>

#define N_NODES 50000
#define N_EDGES 600000
#define D 128
#define N_RELS 460

typedef unsigned short u16;
typedef __attribute__((ext_vector_type(8))) short bf16x8;   // 8 bf16 (4 VGPRs)
typedef __attribute__((ext_vector_type(4))) float f32x4;

// workspace layout (element offsets, 4-byte elements)
enum : int {
    OFF_W       = 0,         //   384 floats  (w = fc1^T @ fc2^T, split w1|w2|w3)
    OFF_S1      = 384,       // 50000 floats
    OFF_S2      = 50384,     // 50000 floats
    OFF_S3      = 100384,    //   460 floats + pad
    OFF_COUNTS  = 100864,    // 50000 ints
    OFF_CURSOR  = 150864,    // 50000 ints
    OFF_OFFSETS = 200864,    // 50001 ints + pad
    OFF_BSUMS   = 250880,    //   256 ints
    OFF_PAIRS   = 251136,    // 600000 int2 = 1200000 ints (CSR slot -> {src, exp(e)})
    OFF_HB      = 1451136,   // 6400000 bf16 = 3200000 float slots (h in bf16)
    OFF_WT      = 4651136,   // 16384 bf16 = 8192 float slots (loop_weight^T bf16)
};                           // total 4659328 elems = 17.8 MiB

__device__ __forceinline__ u16 f2bf(float f) {
    unsigned u = __float_as_uint(f);
    unsigned r = u + 0x7FFFu + ((u >> 16) & 1u);   // RNE
    return (u16)(r >> 16);
}

// ---------- K0: w[j] = sum_k fc2[k] * fc1[k][j] ----------
__global__ void k_w(const float* __restrict__ fc1, const float* __restrict__ fc2,
                    float* __restrict__ w) {
    int j = threadIdx.x;
    if (j >= 3 * D) return;
    float acc = 0.f;
    for (int k = 0; k < D; ++k) acc += fc2[k] * fc1[k * 3 * D + j];
    w[j] = acc;
}

// ---------- cast + transpose loop_weight: Wt[n][k] = W[k][n] ----------
__global__ void k_cast_w(const float* __restrict__ W, u16* __restrict__ wt) {
    int i = blockIdx.x * blockDim.x + threadIdx.x;      // 16384 threads
    int k = i >> 7, n = i & 127;
    wt[n * D + k] = f2bf(W[k * D + n]);
}

// ---------- K1: per-node s1,s2 + bf16 cast of h; per-rel s3 (one wave/row) ----------
__global__ void k_scores_cast(const float* __restrict__ h, const float* __restrict__ emb_rel,
                              const float* __restrict__ w,
                              float* __restrict__ s1, float* __restrict__ s2,
                              float* __restrict__ s3, u16* __restrict__ hb) {
    int wid  = (blockIdx.x * blockDim.x + threadIdx.x) >> 6;
    int lane = threadIdx.x & 63;
    if (wid < N_NODES) {
        float2 hv = ((const float2*)(h + (size_t)wid * D))[lane];
        // emit bf16 copy of this row (coalesced 4B/lane)
        unsigned pk = (unsigned)f2bf(hv.x) | ((unsigned)f2bf(hv.y) << 16);
        ((unsigned*)hb)[(size_t)wid * (D / 2) + lane] = pk;
        float2 w1 = ((const float2*)(w))[lane];
        float2 w2 = ((const float2*)(w + D))[lane];
        float a1 = hv.x * w1.x + hv.y * w1.y;
        float a2 = hv.x * w2.x + hv.y * w2.y;
        #pragma unroll
        for (int o = 32; o; o >>= 1) { a1 += __shfl_xor(a1, o); a2 += __shfl_xor(a2, o); }
        if (lane == 0) { s1[wid] = a1; s2[wid] = a2; }
    } else if (wid < N_NODES + N_RELS) {
        int r = wid - N_NODES;
        float2 rv = ((const float2*)(emb_rel + (size_t)r * D))[lane];
        float2 w3 = ((const float2*)(w + 2 * D))[lane];
        float a3 = rv.x * w3.x + rv.y * w3.y;
        #pragma unroll
        for (int o = 32; o; o >>= 1) a3 += __shfl_xor(a3, o);
        if (lane == 0) s3[r] = a3;
    }
}

// ---------- K2: in-degree histogram ----------
__global__ void k_count(const int* __restrict__ dst, int* __restrict__ counts) {
    int e = blockIdx.x * blockDim.x + threadIdx.x;
    if (e < N_EDGES) atomicAdd(&counts[dst[e]], 1);
}

// ---------- scan: counts -> offsets (exclusive) ----------
__global__ void k_scan1(const int* __restrict__ counts, int* __restrict__ offsets,
                        int* __restrict__ bsums) {
    __shared__ int s[256];
    int i = blockIdx.x * 256 + threadIdx.x;
    int v = (i < N_NODES) ? counts[i] : 0;
    s[threadIdx.x] = v;
    __syncthreads();
    for (int off = 1; off < 256; off <<= 1) {
        int t = (threadIdx.x >= off) ? s[threadIdx.x - off] : 0;
        __syncthreads();
        s[threadIdx.x] += t;
        __syncthreads();
    }
    if (i < N_NODES) offsets[i + 1] = s[threadIdx.x];
    if (blockIdx.x == 0 && threadIdx.x == 0) offsets[0] = 0;
    if (threadIdx.x == 255) bsums[blockIdx.x] = s[255];
}

__global__ void k_scan2(int* __restrict__ bsums, int nb) {
    __shared__ int s[256];
    int t = threadIdx.x;
    s[t] = (t < nb) ? bsums[t] : 0;
    __syncthreads();
    for (int off = 1; off < 256; off <<= 1) {
        int v = (t >= off) ? s[t - off] : 0;
        __syncthreads();
        s[t] += v;
        __syncthreads();
    }
    if (t < nb) bsums[t] = s[t];
}

__global__ void k_scan3(int* __restrict__ offsets, const int* __restrict__ bsums) {
    int i = blockIdx.x * 256 + threadIdx.x;
    if (i < N_NODES && blockIdx.x > 0) offsets[i + 1] += bsums[blockIdx.x - 1];
}

// ---------- K3: exp(leaky(e)) + CSR slot placement (single 8B scattered store) ----------
__global__ void k_scatter(const int* __restrict__ src, const int* __restrict__ dst,
                          const int* __restrict__ typ,
                          const float* __restrict__ s1, const float* __restrict__ s2,
                          const float* __restrict__ s3,
                          const int* __restrict__ offsets, int* __restrict__ cursor,
                          int2* __restrict__ pairs) {
    int e = blockIdx.x * blockDim.x + threadIdx.x;
    if (e >= N_EDGES) return;
    int d = dst[e];
    int sidx = src[e];
    float x = s1[sidx] + s2[d] + s3[typ[e]];
    float lv = (x > 0.f) ? x : 0.01f * x;
    float ex = __expf(lv);                 // |x| small; no max-sub needed (shift-invariant)
    int slot = offsets[d] + atomicAdd(&cursor[d], 1);
    pairs[slot] = make_int2(sidx, __float_as_int(ex));
}

// ---------- K5: out = h @ loop_weight via bf16 MFMA ----------
// A-frag: A[m=lane&15][k=quad*8+j]; B-frag: B[k=quad*8+j][n=lane&15];
// C/D: D[m=quad*4+reg][n=lane&15]. Wt is [n][k] so B loads are contiguous.
#define WT_STRIDE 136   // bf16 elems per LDS row: 272 B -> 16B-aligned b128, bank-balanced
__global__ __launch_bounds__(256) void k_gemm_mfma(const u16* __restrict__ hb,
                                                   const u16* __restrict__ wt,
                                                   float* __restrict__ out) {
    __shared__ u16 Ws[D * WT_STRIDE];                   // 34 KiB
    int t = threadIdx.x;
    for (int i = t; i < (D * D) / 8; i += 256) {        // 2048 segs of 8 bf16
        int row = i >> 4, seg = i & 15;
        *(bf16x8*)(&Ws[row * WT_STRIDE + seg * 8]) = *(const bf16x8*)(&wt[row * D + seg * 8]);
    }
    __syncthreads();

    int wave = t >> 6, lane = t & 63;
    int quad = lane >> 4, m16 = lane & 15;
    int nbase = blockIdx.x * 64 + wave * 16;

    f32x4 acc[8];
    #pragma unroll
    for (int cg = 0; cg < 8; ++cg) acc[cg] = (f32x4){0.f, 0.f, 0.f, 0.f};

    int arow = nbase + m16;
    if (arow >= N_NODES) arow = N_NODES - 1;            // clamp; stores are guarded
    const u16* aptr = hb + (size_t)arow * D + quad * 8;

    #pragma unroll
    for (int k0 = 0; k0 < D; k0 += 32) {
        bf16x8 a = *(const bf16x8*)(aptr + k0);
        #pragma unroll
        for (int cg = 0; cg < 8; ++cg) {
            bf16x8 b = *(const bf16x8*)(&Ws[(cg * 16 + m16) * WT_STRIDE + k0 + quad * 8]);
            acc[cg] = __builtin_amdgcn_mfma_f32_16x16x32_bf16(a, b, acc[cg], 0, 0, 0);
        }
    }

    #pragma unroll
    for (int reg = 0; reg < 4; ++reg) {
        int row = nbase + quad * 4 + reg;
        if (row < N_NODES) {
            #pragma unroll
            for (int cg = 0; cg < 8; ++cg)
                out[(size_t)row * D + cg * 16 + m16] = acc[cg][reg];
        }
    }
}

// ---------- K4: per-node softmax-normalize + weighted gather (bf16 rows) ----------
__global__ void k_gather(const u16* __restrict__ hb, const int* __restrict__ offsets,
                         const int2* __restrict__ pairs, float* __restrict__ out) {
    int n    = (blockIdx.x * blockDim.x + threadIdx.x) >> 6;
    int lane = threadIdx.x & 63;
    if (n >= N_NODES) return;
    int beg = offsets[n], end = offsets[n + 1];
    if (beg == end) return;                              // deg 0: out = h@W only

    int   msrc = 0;
    float mex  = 0.f;
    {
        int i = beg + lane;
        if (i < end) { int2 p = pairs[i]; msrc = p.x; mex = __int_as_float(p.y); }
    }
    float den = mex;
    // nodes with degree > 64: accumulate remaining exps (rare path)
    for (int i = beg + 64 + lane; i < end; i += 64) den += __int_as_float(pairs[i].y);
    #pragma unroll
    for (int o = 32; o; o >>= 1) den += __shfl_xor(den, o);
    float inv = 1.f / den;

    float2 acc = {0.f, 0.f};
    for (int cb = beg; cb < end; cb += 64) {
        if (cb != beg) {                                 // reload window (first is preloaded)
            int i = cb + lane;
            msrc = 0; mex = 0.f;
            if (i < end) { int2 p = pairs[i]; msrc = p.x; mex = __int_as_float(p.y); }
        }
        float mco = mex * inv;
        int cnt = min(64, end - cb);
        int j = 0;
        for (; j + 1 < cnt; j += 2) {
            int   s0 = __shfl(msrc, j),     s1 = __shfl(msrc, j + 1);
            float c0 = __shfl(mco, j),      c1 = __shfl(mco, j + 1);
            unsigned u0 = ((const unsigned*)(hb + (size_t)s0 * D))[lane];
            unsigned u1 = ((const unsigned*)(hb + (size_t)s1 * D))[lane];
            acc.x += c0 * __uint_as_float(u0 << 16) + c1 * __uint_as_float(u1 << 16);
            acc.y += c0 * __uint_as_float(u0 & 0xFFFF0000u) + c1 * __uint_as_float(u1 & 0xFFFF0000u);
        }
        if (j < cnt) {
            int   s0 = __shfl(msrc, j);
            float c0 = __shfl(mco, j);
            unsigned u0 = ((const unsigned*)(hb + (size_t)s0 * D))[lane];
            acc.x += c0 * __uint_as_float(u0 << 16);
            acc.y += c0 * __uint_as_float(u0 & 0xFFFF0000u);
        }
    }
    float2* op = (float2*)(out + (size_t)n * D);
    float2 cur = op[lane];
    op[lane] = make_float2(cur.x + acc.x, cur.y + acc.y);
}

extern "C" void kernel_launch(void* const* d_in, const int* in_sizes, int n_in,
                              void* d_out, int out_size, void* d_ws, size_t ws_size,
                              hipStream_t stream) {
    const float* h       = (const float*)d_in[0];
    const float* emb_rel = (const float*)d_in[1];
    const float* fc1     = (const float*)d_in[2];   // [D, 3D]
    const float* fc2     = (const float*)d_in[3];   // [1, D]
    const float* loopw   = (const float*)d_in[4];   // [D, D]
    const int*   esrc    = (const int*)d_in[5];
    const int*   edst    = (const int*)d_in[6];
    const int*   etyp    = (const int*)d_in[7];
    float* out = (float*)d_out;
    float* ws  = (float*)d_ws;

    float* w       = ws + OFF_W;
    float* s1      = ws + OFF_S1;
    float* s2      = ws + OFF_S2;
    float* s3      = ws + OFF_S3;
    int*   counts  = (int*)(ws + OFF_COUNTS);
    int*   cursor  = (int*)(ws + OFF_CURSOR);
    int*   offsets = (int*)(ws + OFF_OFFSETS);
    int*   bsums   = (int*)(ws + OFF_BSUMS);
    int2*  pairs   = (int2*)(ws + OFF_PAIRS);
    u16*   hb      = (u16*)(ws + OFF_HB);
    u16*   wt      = (u16*)(ws + OFF_WT);

    // zero counts + cursor (contiguous 100000 ints)
    hipMemsetAsync(counts, 0, 100000 * sizeof(int), stream);

    k_w<<<1, 384, 0, stream>>>(fc1, fc2, w);
    k_cast_w<<<(D * D + 255) / 256, 256, 0, stream>>>(loopw, wt);

    int score_blocks = (N_NODES + N_RELS + 3) / 4;
    k_scores_cast<<<score_blocks, 256, 0, stream>>>(h, emb_rel, w, s1, s2, s3, hb);

    int edge_blocks = (N_EDGES + 255) / 256;
    k_count<<<edge_blocks, 256, 0, stream>>>(edst, counts);

    int scan_blocks = (N_NODES + 255) / 256;             // 196
    k_scan1<<<scan_blocks, 256, 0, stream>>>(counts, offsets, bsums);
    k_scan2<<<1, 256, 0, stream>>>(bsums, scan_blocks);
    k_scan3<<<scan_blocks, 256, 0, stream>>>(offsets, bsums);

    k_scatter<<<edge_blocks, 256, 0, stream>>>(esrc, edst, etyp, s1, s2, s3,
                                               offsets, cursor, pairs);

    k_gemm_mfma<<<(N_NODES + 63) / 64, 256, 0, stream>>>(hb, wt, out);

    int gather_blocks = (N_NODES + 3) / 4;
    k_gather<<<gather_blocks, 256, 0, stream>>>(hb, offsets, pairs, out);
}

// Round 4
// 218.004 us; speedup vs baseline: 1.3390x; 1.0020x over previous
//
#include <hip/hip_runtime.h>
#include <hip/hip_fp16.h>

#define N_NODES 50000
#define N_EDGES 600000
#define D 128
#define N_RELS 460

typedef unsigned short u16;
typedef __attribute__((ext_vector_type(8))) short bf16x8;   // 8 bf16 (4 VGPRs)
typedef __attribute__((ext_vector_type(4))) float f32x4;

// workspace layout (element offsets, 4-byte elements)
enum : int {
    OFF_W       = 0,         //   384 floats  (w = fc1^T @ fc2^T, split w1|w2|w3)
    OFF_S1      = 384,       // 50000 floats
    OFF_S2      = 50384,     // 50000 floats
    OFF_S3      = 100384,    //   460 floats + pad
    OFF_COUNTS  = 100864,    // 50000 ints
    OFF_CURSOR  = 150864,    // 50000 ints   (contiguous with counts: zeroed together)
    OFF_OFFSETS = 200864,    // 50001 ints + pad (block-local inclusive scans)
    OFF_BSUMS   = 250880,    //   256 ints   (scanned block sums)
    OFF_PAIRS   = 251136,    // 600000 uints (CSR slot -> src(16b) | half(exp(e))(16b))
    OFF_HB      = 851136,    // 6400000 bf16 = 3200000 float slots (h in bf16)
    OFF_WT      = 4051136,   // 16384 bf16 = 8192 float slots (loop_weight^T bf16)
};                           // total ~15.5 MiB

#define SCORE_BLOCKS 12616   // ceil((N_NODES + N_RELS)/4) waves of 64
#define CNT_BLOCKS   586     // ceil(150000/256) int4-edge threads
#define ZERO_BLOCKS  391     // ceil(100000/256)

__device__ __forceinline__ u16 f2bf(float f) {
    unsigned u = __float_as_uint(f);
    unsigned r = u + 0x7FFFu + ((u >> 16) & 1u);   // RNE
    return (u16)(r >> 16);
}

// ---------- K0: fused prep — w vector, Wt bf16 transpose, zero counts+cursor ----------
__global__ void k_prep(const float* __restrict__ fc1, const float* __restrict__ fc2,
                       const float* __restrict__ W,
                       float* __restrict__ w, u16* __restrict__ wt,
                       int* __restrict__ cc) {
    int b = blockIdx.x, t = threadIdx.x;
    if (b == 0) {
        for (int j = t; j < 3 * D; j += 256) {
            float acc = 0.f;
            for (int k = 0; k < D; ++k) acc += fc2[k] * fc1[k * 3 * D + j];
            w[j] = acc;
        }
    } else if (b <= 64) {
        int i = (b - 1) * 256 + t;                 // 16384 elems
        int k = i >> 7, n = i & 127;
        wt[n * D + k] = f2bf(W[k * D + n]);
    } else {
        int i = (b - 65) * 256 + t;                // zero 100000 ints
        if (i < 100000) cc[i] = 0;
    }
}

// ---------- K1: per-node s1,s2 + bf16 cast of h; per-rel s3; edge histogram ----------
__global__ void k_scores_cast_count(const float* __restrict__ h,
                                    const float* __restrict__ emb_rel,
                                    const float* __restrict__ w,
                                    float* __restrict__ s1, float* __restrict__ s2,
                                    float* __restrict__ s3, u16* __restrict__ hb,
                                    const int* __restrict__ dst,
                                    int* __restrict__ counts) {
    if (blockIdx.x < SCORE_BLOCKS) {
        int wid  = (blockIdx.x * blockDim.x + threadIdx.x) >> 6;
        int lane = threadIdx.x & 63;
        if (wid < N_NODES) {
            float2 hv = ((const float2*)(h + (size_t)wid * D))[lane];
            unsigned pk = (unsigned)f2bf(hv.x) | ((unsigned)f2bf(hv.y) << 16);
            ((unsigned*)hb)[(size_t)wid * (D / 2) + lane] = pk;
            float2 w1 = ((const float2*)(w))[lane];
            float2 w2 = ((const float2*)(w + D))[lane];
            float a1 = hv.x * w1.x + hv.y * w1.y;
            float a2 = hv.x * w2.x + hv.y * w2.y;
            #pragma unroll
            for (int o = 32; o; o >>= 1) { a1 += __shfl_xor(a1, o); a2 += __shfl_xor(a2, o); }
            if (lane == 0) { s1[wid] = a1; s2[wid] = a2; }
        } else if (wid < N_NODES + N_RELS) {
            int r = wid - N_NODES;
            float2 rv = ((const float2*)(emb_rel + (size_t)r * D))[lane];
            float2 w3 = ((const float2*)(w + 2 * D))[lane];
            float a3 = rv.x * w3.x + rv.y * w3.y;
            #pragma unroll
            for (int o = 32; o; o >>= 1) a3 += __shfl_xor(a3, o);
            if (lane == 0) s3[r] = a3;
        }
    } else {
        int i = (blockIdx.x - SCORE_BLOCKS) * 256 + threadIdx.x;   // int4 over 600000 edges
        if (i < N_EDGES / 4) {
            int4 d4 = ((const int4*)dst)[i];
            atomicAdd(&counts[d4.x], 1);
            atomicAdd(&counts[d4.y], 1);
            atomicAdd(&counts[d4.z], 1);
            atomicAdd(&counts[d4.w], 1);
        }
    }
}

// ---------- scan1: per-block inclusive scan; offsets[i+1]=incl(i), bsums[b]=block sum ----------
__global__ void k_scan1(const int* __restrict__ counts, int* __restrict__ offsets,
                        int* __restrict__ bsums) {
    __shared__ int s[256];
    int i = blockIdx.x * 256 + threadIdx.x;
    int v = (i < N_NODES) ? counts[i] : 0;
    s[threadIdx.x] = v;
    __syncthreads();
    for (int off = 1; off < 256; off <<= 1) {
        int t = (threadIdx.x >= off) ? s[threadIdx.x - off] : 0;
        __syncthreads();
        s[threadIdx.x] += t;
        __syncthreads();
    }
    if (i < N_NODES) offsets[i + 1] = s[threadIdx.x];
    if (blockIdx.x == 0 && threadIdx.x == 0) offsets[0] = 0;
    if (threadIdx.x == 255) bsums[blockIdx.x] = s[255];
}

// ---------- scan2: inclusive scan of block sums (196 <= 256) ----------
__global__ void k_scan2(int* __restrict__ bsums, int nb) {
    __shared__ int s[256];
    int t = threadIdx.x;
    s[t] = (t < nb) ? bsums[t] : 0;
    __syncthreads();
    for (int off = 1; off < 256; off <<= 1) {
        int v = (t >= off) ? s[t - off] : 0;
        __syncthreads();
        s[t] += v;
        __syncthreads();
    }
    if (t < nb) bsums[t] = s[t];
}

// global exclusive offset of node d from block-local scans + scanned bsums
__device__ __forceinline__ int g_off(const int* offsets, const int* bsums, int d) {
    int blk = d >> 8;
    int base = blk ? bsums[blk - 1] : 0;
    return ((d & 255) ? offsets[d] : 0) + base;
}

// ---------- K3: exp(leaky(e)) + CSR slot placement (single 4B scattered store) ----------
__global__ void k_scatter(const int* __restrict__ src, const int* __restrict__ dst,
                          const int* __restrict__ typ,
                          const float* __restrict__ s1, const float* __restrict__ s2,
                          const float* __restrict__ s3,
                          const int* __restrict__ offsets, const int* __restrict__ bsums,
                          int* __restrict__ cursor, unsigned* __restrict__ pairs) {
    int e = blockIdx.x * blockDim.x + threadIdx.x;
    if (e >= N_EDGES) return;
    int d = dst[e];
    int sidx = src[e];
    float x = s1[sidx] + s2[d] + s3[typ[e]];
    float lv = (x > 0.f) ? x : 0.01f * x;
    float ex = __expf(lv);                 // |x| <~ 3; no max-sub needed (shift-invariant)
    int slot = g_off(offsets, bsums, d) + atomicAdd(&cursor[d], 1);
    unsigned pk = (unsigned)sidx
                | ((unsigned)__half_as_ushort(__float2half(ex)) << 16);
    pairs[slot] = pk;
}

// ---------- K5: out = h @ loop_weight via bf16 MFMA ----------
#define WT_STRIDE 136   // bf16 elems per LDS row: 272 B -> 16B-aligned b128
__global__ __launch_bounds__(256) void k_gemm_mfma(const u16* __restrict__ hb,
                                                   const u16* __restrict__ wt,
                                                   float* __restrict__ out) {
    __shared__ u16 Ws[D * WT_STRIDE];                   // 34 KiB
    int t = threadIdx.x;
    for (int i = t; i < (D * D) / 8; i += 256) {
        int row = i >> 4, seg = i & 15;
        *(bf16x8*)(&Ws[row * WT_STRIDE + seg * 8]) = *(const bf16x8*)(&wt[row * D + seg * 8]);
    }
    __syncthreads();

    int wave = t >> 6, lane = t & 63;
    int quad = lane >> 4, m16 = lane & 15;
    int nbase = blockIdx.x * 64 + wave * 16;

    f32x4 acc[8];
    #pragma unroll
    for (int cg = 0; cg < 8; ++cg) acc[cg] = (f32x4){0.f, 0.f, 0.f, 0.f};

    int arow = nbase + m16;
    if (arow >= N_NODES) arow = N_NODES - 1;            // clamp; stores guarded
    const u16* aptr = hb + (size_t)arow * D + quad * 8;

    #pragma unroll
    for (int k0 = 0; k0 < D; k0 += 32) {
        bf16x8 a = *(const bf16x8*)(aptr + k0);
        #pragma unroll
        for (int cg = 0; cg < 8; ++cg) {
            bf16x8 b = *(const bf16x8*)(&Ws[(cg * 16 + m16) * WT_STRIDE + k0 + quad * 8]);
            acc[cg] = __builtin_amdgcn_mfma_f32_16x16x32_bf16(a, b, acc[cg], 0, 0, 0);
        }
    }

    #pragma unroll
    for (int reg = 0; reg < 4; ++reg) {
        int row = nbase + quad * 4 + reg;
        if (row < N_NODES) {
            #pragma unroll
            for (int cg = 0; cg < 8; ++cg)
                out[(size_t)row * D + cg * 16 + m16] = acc[cg][reg];
        }
    }
}

// ---------- K4: per-node softmax-normalize + weighted gather (bf16 rows) ----------
__device__ __forceinline__ float unp_ex(unsigned p) {
    return __half2float(__ushort_as_half((u16)(p >> 16)));
}

__global__ void k_gather(const u16* __restrict__ hb, const int* __restrict__ offsets,
                         const int* __restrict__ bsums,
                         const unsigned* __restrict__ pairs, float* __restrict__ out) {
    int n    = (blockIdx.x * blockDim.x + threadIdx.x) >> 6;
    int lane = threadIdx.x & 63;
    if (n >= N_NODES) return;
    int blk = n >> 8;
    int base = blk ? bsums[blk - 1] : 0;
    int beg = ((n & 255) ? offsets[n] : 0) + base;
    int end = offsets[n + 1] + base;
    if (beg == end) return;                              // deg 0: out = h@W only

    unsigned p0 = 0;
    {
        int i = beg + lane;
        if (i < end) p0 = pairs[i];
    }
    float mex = unp_ex(p0);
    float den = mex;
    for (int i = beg + 64 + lane; i < end; i += 64) den += unp_ex(pairs[i]);  // deg>64 tail
    #pragma unroll
    for (int o = 32; o; o >>= 1) den += __shfl_xor(den, o);
    float inv = 1.f / den;

    float2 acc = {0.f, 0.f};
    for (int cb = beg; cb < end; cb += 64) {
        int msrc; float mco;
        if (cb == beg) { msrc = (int)(p0 & 0xFFFFu); mco = mex * inv; }
        else {
            int i = cb + lane;
            unsigned p = (i < end) ? pairs[i] : 0u;
            msrc = (int)(p & 0xFFFFu);
            mco  = unp_ex(p) * inv;
            if (i >= end) mco = 0.f;
        }
        int cnt = min(64, end - cb);
        int j = 0;
        for (; j + 3 < cnt; j += 4) {
            int   a0 = __shfl(msrc, j),     a1 = __shfl(msrc, j + 1);
            int   a2 = __shfl(msrc, j + 2), a3 = __shfl(msrc, j + 3);
            float c0 = __shfl(mco, j),      c1 = __shfl(mco, j + 1);
            float c2 = __shfl(mco, j + 2),  c3 = __shfl(mco, j + 3);
            unsigned u0 = ((const unsigned*)(hb + (size_t)a0 * D))[lane];
            unsigned u1 = ((const unsigned*)(hb + (size_t)a1 * D))[lane];
            unsigned u2 = ((const unsigned*)(hb + (size_t)a2 * D))[lane];
            unsigned u3 = ((const unsigned*)(hb + (size_t)a3 * D))[lane];
            acc.x += c0 * __uint_as_float(u0 << 16) + c1 * __uint_as_float(u1 << 16)
                   + c2 * __uint_as_float(u2 << 16) + c3 * __uint_as_float(u3 << 16);
            acc.y += c0 * __uint_as_float(u0 & 0xFFFF0000u) + c1 * __uint_as_float(u1 & 0xFFFF0000u)
                   + c2 * __uint_as_float(u2 & 0xFFFF0000u) + c3 * __uint_as_float(u3 & 0xFFFF0000u);
        }
        for (; j < cnt; ++j) {
            int   a0 = __shfl(msrc, j);
            float c0 = __shfl(mco, j);
            unsigned u0 = ((const unsigned*)(hb + (size_t)a0 * D))[lane];
            acc.x += c0 * __uint_as_float(u0 << 16);
            acc.y += c0 * __uint_as_float(u0 & 0xFFFF0000u);
        }
    }
    float2* op = (float2*)(out + (size_t)n * D);
    float2 cur = op[lane];
    op[lane] = make_float2(cur.x + acc.x, cur.y + acc.y);
}

extern "C" void kernel_launch(void* const* d_in, const int* in_sizes, int n_in,
                              void* d_out, int out_size, void* d_ws, size_t ws_size,
                              hipStream_t stream) {
    const float* h       = (const float*)d_in[0];
    const float* emb_rel = (const float*)d_in[1];
    const float* fc1     = (const float*)d_in[2];   // [D, 3D]
    const float* fc2     = (const float*)d_in[3];   // [1, D]
    const float* loopw   = (const float*)d_in[4];   // [D, D]
    const int*   esrc    = (const int*)d_in[5];
    const int*   edst    = (const int*)d_in[6];
    const int*   etyp    = (const int*)d_in[7];
    float* out = (float*)d_out;
    float* ws  = (float*)d_ws;

    float*    w       = ws + OFF_W;
    float*    s1      = ws + OFF_S1;
    float*    s2      = ws + OFF_S2;
    float*    s3      = ws + OFF_S3;
    int*      counts  = (int*)(ws + OFF_COUNTS);
    int*      cursor  = (int*)(ws + OFF_CURSOR);
    int*      offsets = (int*)(ws + OFF_OFFSETS);
    int*      bsums   = (int*)(ws + OFF_BSUMS);
    unsigned* pairs   = (unsigned*)(ws + OFF_PAIRS);
    u16*      hb      = (u16*)(ws + OFF_HB);
    u16*      wt      = (u16*)(ws + OFF_WT);

    // 1: w + Wt^T bf16 + zero counts/cursor
    k_prep<<<1 + 64 + ZERO_BLOCKS, 256, 0, stream>>>(fc1, fc2, loopw, w, wt, counts);

    // 2: node scores + bf16 cast + edge histogram
    k_scores_cast_count<<<SCORE_BLOCKS + CNT_BLOCKS, 256, 0, stream>>>(
        h, emb_rel, w, s1, s2, s3, hb, edst, counts);

    // 3,4: two-level scan (base-add folded into consumers)
    int scan_blocks = (N_NODES + 255) / 256;             // 196
    k_scan1<<<scan_blocks, 256, 0, stream>>>(counts, offsets, bsums);
    k_scan2<<<1, 256, 0, stream>>>(bsums, scan_blocks);

    // 5: CSR fill
    int edge_blocks = (N_EDGES + 255) / 256;
    k_scatter<<<edge_blocks, 256, 0, stream>>>(esrc, edst, etyp, s1, s2, s3,
                                               offsets, bsums, cursor, pairs);

    // 6: self-loop GEMM (writes out)
    k_gemm_mfma<<<(N_NODES + 63) / 64, 256, 0, stream>>>(hb, wt, out);

    // 7: softmax-normalized weighted gather (RMW out)
    int gather_blocks = (N_NODES + 3) / 4;
    k_gather<<<gather_blocks, 256, 0, stream>>>(hb, offsets, bsums, pairs, out);
}

// Round 5
// 202.286 us; speedup vs baseline: 1.4431x; 1.0777x over previous
//
#include <hip/hip_runtime.h>
#include <hip/hip_fp16.h>

#define N_NODES 50000
#define N_EDGES 600000
#define D 128
#define N_RELS 460

typedef unsigned short u16;
typedef __attribute__((ext_vector_type(8))) short bf16x8;   // 8 bf16 (4 VGPRs)
typedef __attribute__((ext_vector_type(4))) float f32x4;

// workspace layout (element offsets, 4-byte elements)
enum : int {
    OFF_W       = 0,         //   384 floats  (w = fc1^T @ fc2^T, split w1|w2|w3)
    OFF_S1      = 384,       // 50000 floats
    OFF_S2      = 50384,     // 50000 floats
    OFF_S3      = 100384,    //   460 floats + pad
    OFF_COUNTS  = 100864,    // 50000 ints
    OFF_OFFSETS = 150864,    // 50001 ints + pad (block-local inclusive scans)
    OFF_BSUMS   = 200880,    //   256 ints (scanned block sums)
    OFF_RANK    = 201136,    // 600000 ints  (edge -> rank within its dst)
    OFF_PAIRS   = 801136,    // 600000 uints (CSR slot -> src(16b) | half(exp)(16b))
    OFF_HB      = 1401136,   // 6400000 bf16 = 3200000 float slots (h in bf16)
    OFF_WT      = 4601136,   // 16384 bf16 = 8192 float slots (loop_weight^T bf16)
};                           // total ~17.6 MiB

#define SCORE_BLOCKS 12615   // (N_NODES+N_RELS)/4 waves of 64
#define CNT_BLOCKS   586     // ceil(150000/256) int4-edge threads
#define ZERO_BLOCKS  196     // ceil(50000/256)
#define EDGE_BLOCKS  2344    // ceil(600000/256)
#define GEMM_BLOCKS  782     // ceil(50000/64)

__device__ __forceinline__ u16 f2bf(float f) {
    unsigned u = __float_as_uint(f);
    unsigned r = u + 0x7FFFu + ((u >> 16) & 1u);   // RNE
    return (u16)(r >> 16);
}
__device__ __forceinline__ float unp_ex(unsigned p) {
    return __half2float(__ushort_as_half((u16)(p >> 16)));
}

// ---------- K0: fused prep — w vector, Wt bf16 transpose, zero counts ----------
__global__ void k_prep(const float* __restrict__ fc1, const float* __restrict__ fc2,
                       const float* __restrict__ W,
                       float* __restrict__ w, u16* __restrict__ wt,
                       int* __restrict__ counts) {
    int b = blockIdx.x, t = threadIdx.x;
    if (b == 0) {
        for (int j = t; j < 3 * D; j += 256) {
            float acc = 0.f;
            for (int k = 0; k < D; ++k) acc += fc2[k] * fc1[k * 3 * D + j];
            w[j] = acc;
        }
    } else if (b <= 64) {
        int i = (b - 1) * 256 + t;                 // 16384 elems
        int k = i >> 7, n = i & 127;
        wt[n * D + k] = f2bf(W[k * D + n]);
    } else {
        int i = (b - 65) * 256 + t;                // zero 50000 ints
        if (i < N_NODES) counts[i] = 0;
    }
}

// ---------- K1: node scores + bf16 cast of h; rel s3; edge histogram + RANK ----------
__global__ void k_scores_cast_count(const float* __restrict__ h,
                                    const float* __restrict__ emb_rel,
                                    const float* __restrict__ w,
                                    float* __restrict__ s1, float* __restrict__ s2,
                                    float* __restrict__ s3, u16* __restrict__ hb,
                                    const int* __restrict__ dst,
                                    int* __restrict__ counts,
                                    int* __restrict__ rank) {
    if (blockIdx.x < SCORE_BLOCKS) {
        int wid  = (blockIdx.x * blockDim.x + threadIdx.x) >> 6;
        int lane = threadIdx.x & 63;
        if (wid < N_NODES) {
            float2 hv = ((const float2*)(h + (size_t)wid * D))[lane];
            unsigned pk = (unsigned)f2bf(hv.x) | ((unsigned)f2bf(hv.y) << 16);
            ((unsigned*)hb)[(size_t)wid * (D / 2) + lane] = pk;
            float2 w1 = ((const float2*)(w))[lane];
            float2 w2 = ((const float2*)(w + D))[lane];
            float a1 = hv.x * w1.x + hv.y * w1.y;
            float a2 = hv.x * w2.x + hv.y * w2.y;
            #pragma unroll
            for (int o = 32; o; o >>= 1) { a1 += __shfl_xor(a1, o); a2 += __shfl_xor(a2, o); }
            if (lane == 0) { s1[wid] = a1; s2[wid] = a2; }
        } else if (wid < N_NODES + N_RELS) {
            int r = wid - N_NODES;
            float2 rv = ((const float2*)(emb_rel + (size_t)r * D))[lane];
            float2 w3 = ((const float2*)(w + 2 * D))[lane];
            float a3 = rv.x * w3.x + rv.y * w3.y;
            #pragma unroll
            for (int o = 32; o; o >>= 1) a3 += __shfl_xor(a3, o);
            if (lane == 0) s3[r] = a3;
        }
    } else {
        int i = (blockIdx.x - SCORE_BLOCKS) * 256 + threadIdx.x;   // int4 over edges
        if (i < N_EDGES / 4) {
            int4 d4 = ((const int4*)dst)[i];
            int4 r4;
            r4.x = atomicAdd(&counts[d4.x], 1);
            r4.y = atomicAdd(&counts[d4.y], 1);
            r4.z = atomicAdd(&counts[d4.z], 1);
            r4.w = atomicAdd(&counts[d4.w], 1);
            ((int4*)rank)[i] = r4;                  // coalesced: rank within dst
        }
    }
}

// ---------- scan1: per-block inclusive scan; offsets[i+1]=incl(i), bsums[b]=sum ----------
__global__ void k_scan1(const int* __restrict__ counts, int* __restrict__ offsets,
                        int* __restrict__ bsums) {
    __shared__ int s[256];
    int i = blockIdx.x * 256 + threadIdx.x;
    int v = (i < N_NODES) ? counts[i] : 0;
    s[threadIdx.x] = v;
    __syncthreads();
    for (int off = 1; off < 256; off <<= 1) {
        int t = (threadIdx.x >= off) ? s[threadIdx.x - off] : 0;
        __syncthreads();
        s[threadIdx.x] += t;
        __syncthreads();
    }
    if (i < N_NODES) offsets[i + 1] = s[threadIdx.x];
    if (blockIdx.x == 0 && threadIdx.x == 0) offsets[0] = 0;
    if (threadIdx.x == 255) bsums[blockIdx.x] = s[255];
}

// ---------- scan2: inclusive scan of block sums (196 <= 256) ----------
__global__ void k_scan2(int* __restrict__ bsums, int nb) {
    __shared__ int s[256];
    int t = threadIdx.x;
    s[t] = (t < nb) ? bsums[t] : 0;
    __syncthreads();
    for (int off = 1; off < 256; off <<= 1) {
        int v = (t >= off) ? s[t - off] : 0;
        __syncthreads();
        s[t] += v;
        __syncthreads();
    }
    if (t < nb) bsums[t] = s[t];
}

// global exclusive offset of node d
__device__ __forceinline__ int g_off(const int* offsets, const int* bsums, int d) {
    int blk = d >> 8;
    int base = blk ? bsums[blk - 1] : 0;
    return ((d & 255) ? offsets[d] : 0) + base;
}

// ---------- K3: fused {atomic-free CSR fill} + {LDS-free MFMA self-loop GEMM} ----------
// A-frag: A[m=lane&15][k=quad*8+j]; B-frag: B[k=quad*8+j][n=lane&15];
// C/D: D[m=quad*4+reg][n=lane&15]. Wt[n][k] row-major -> B loads contiguous 16B.
__global__ __launch_bounds__(256) void k_scatter_gemm(
        const int* __restrict__ src, const int* __restrict__ dst,
        const int* __restrict__ typ, const int* __restrict__ rank,
        const float* __restrict__ s1, const float* __restrict__ s2,
        const float* __restrict__ s3,
        const int* __restrict__ offsets, const int* __restrict__ bsums,
        unsigned* __restrict__ pairs,
        const u16* __restrict__ hb, const u16* __restrict__ wt,
        float* __restrict__ out) {
    if (blockIdx.x < EDGE_BLOCKS) {
        int e = blockIdx.x * blockDim.x + threadIdx.x;
        if (e >= N_EDGES) return;
        int d = dst[e];
        int sidx = src[e];
        float x = s1[sidx] + s2[d] + s3[typ[e]];
        float lv = (x > 0.f) ? x : 0.01f * x;
        float ex = __expf(lv);             // |x| <~ 3; shift-invariant, no max-sub
        int slot = g_off(offsets, bsums, d) + rank[e];   // NO atomic
        pairs[slot] = (unsigned)sidx
                    | ((unsigned)__half_as_ushort(__float2half(ex)) << 16);
    } else {
        int b = blockIdx.x - EDGE_BLOCKS;
        int t = threadIdx.x;
        int wave = t >> 6, lane = t & 63;
        int quad = lane >> 4, m16 = lane & 15;
        int nbase = b * 64 + wave * 16;

        f32x4 acc[8];
        #pragma unroll
        for (int cg = 0; cg < 8; ++cg) acc[cg] = (f32x4){0.f, 0.f, 0.f, 0.f};

        int arow = nbase + m16;
        if (arow >= N_NODES) arow = N_NODES - 1;         // clamp; stores guarded
        const u16* aptr = hb + (size_t)arow * D + quad * 8;

        #pragma unroll
        for (int k0 = 0; k0 < D; k0 += 32) {
            bf16x8 a = *(const bf16x8*)(aptr + k0);
            #pragma unroll
            for (int cg = 0; cg < 8; ++cg) {
                bf16x8 bb = *(const bf16x8*)(&wt[(size_t)(cg * 16 + m16) * D + k0 + quad * 8]);
                acc[cg] = __builtin_amdgcn_mfma_f32_16x16x32_bf16(a, bb, acc[cg], 0, 0, 0);
            }
        }
        #pragma unroll
        for (int reg = 0; reg < 4; ++reg) {
            int row = nbase + quad * 4 + reg;
            if (row < N_NODES) {
                #pragma unroll
                for (int cg = 0; cg < 8; ++cg)
                    out[(size_t)row * D + cg * 16 + m16] = acc[cg][reg];
            }
        }
    }
}

// ---------- K4: gather — 4 nodes/wave, 16-lane groups, 16B row loads ----------
__global__ void k_gather(const u16* __restrict__ hb, const int* __restrict__ offsets,
                         const int* __restrict__ bsums,
                         const unsigned* __restrict__ pairs, float* __restrict__ out) {
    int n  = (blockIdx.x * blockDim.x + threadIdx.x) >> 4;   // one 16-lane group per node
    int gl = threadIdx.x & 15;
    if (n >= N_NODES) return;
    int blk = n >> 8;
    int base = blk ? bsums[blk - 1] : 0;
    int beg = ((n & 255) ? offsets[n] : 0) + base;
    int end = offsets[n + 1] + base;
    if (beg == end) return;                              // deg 0: out = h@W only

    float den = 0.f;
    for (int i = beg + gl; i < end; i += 16) den += unp_ex(pairs[i]);
    #pragma unroll
    for (int o = 8; o; o >>= 1) den += __shfl_xor(den, o, 16);
    float inv = 1.f / den;

    // lane gl covers columns [8*gl, 8*gl+8)
    f32x4 accA = {0.f, 0.f, 0.f, 0.f}, accB = {0.f, 0.f, 0.f, 0.f};
    for (int cb = beg; cb < end; cb += 16) {
        int i = cb + gl;
        unsigned p = (i < end) ? pairs[i] : 0u;
        int   msrc = (int)(p & 0xFFFFu);
        float mco  = (i < end) ? unp_ex(p) * inv : 0.f;
        int cnt = min(16, end - cb);
        int j = 0;
        for (; j + 1 < cnt; j += 2) {
            int   a0 = __shfl(msrc, j, 16), a1 = __shfl(msrc, j + 1, 16);
            float c0 = __shfl(mco,  j, 16), c1 = __shfl(mco,  j + 1, 16);
            uint4 u0 = ((const uint4*)(hb + (size_t)a0 * D))[gl];
            uint4 u1 = ((const uint4*)(hb + (size_t)a1 * D))[gl];
            accA.x += c0 * __uint_as_float(u0.x << 16) + c1 * __uint_as_float(u1.x << 16);
            accA.y += c0 * __uint_as_float(u0.x & 0xFFFF0000u) + c1 * __uint_as_float(u1.x & 0xFFFF0000u);
            accA.z += c0 * __uint_as_float(u0.y << 16) + c1 * __uint_as_float(u1.y << 16);
            accA.w += c0 * __uint_as_float(u0.y & 0xFFFF0000u) + c1 * __uint_as_float(u1.y & 0xFFFF0000u);
            accB.x += c0 * __uint_as_float(u0.z << 16) + c1 * __uint_as_float(u1.z << 16);
            accB.y += c0 * __uint_as_float(u0.z & 0xFFFF0000u) + c1 * __uint_as_float(u1.z & 0xFFFF0000u);
            accB.z += c0 * __uint_as_float(u0.w << 16) + c1 * __uint_as_float(u1.w << 16);
            accB.w += c0 * __uint_as_float(u0.w & 0xFFFF0000u) + c1 * __uint_as_float(u1.w & 0xFFFF0000u);
        }
        if (j < cnt) {
            int   a0 = __shfl(msrc, j, 16);
            float c0 = __shfl(mco,  j, 16);
            uint4 u0 = ((const uint4*)(hb + (size_t)a0 * D))[gl];
            accA.x += c0 * __uint_as_float(u0.x << 16);
            accA.y += c0 * __uint_as_float(u0.x & 0xFFFF0000u);
            accA.z += c0 * __uint_as_float(u0.y << 16);
            accA.w += c0 * __uint_as_float(u0.y & 0xFFFF0000u);
            accB.x += c0 * __uint_as_float(u0.z << 16);
            accB.y += c0 * __uint_as_float(u0.z & 0xFFFF0000u);
            accB.z += c0 * __uint_as_float(u0.w << 16);
            accB.w += c0 * __uint_as_float(u0.w & 0xFFFF0000u);
        }
    }
    float* op = out + (size_t)n * D + gl * 8;
    float4 o0 = *(float4*)op, o1 = *(float4*)(op + 4);
    o0.x += accA.x; o0.y += accA.y; o0.z += accA.z; o0.w += accA.w;
    o1.x += accB.x; o1.y += accB.y; o1.z += accB.z; o1.w += accB.w;
    *(float4*)op = o0; *(float4*)(op + 4) = o1;
}

extern "C" void kernel_launch(void* const* d_in, const int* in_sizes, int n_in,
                              void* d_out, int out_size, void* d_ws, size_t ws_size,
                              hipStream_t stream) {
    const float* h       = (const float*)d_in[0];
    const float* emb_rel = (const float*)d_in[1];
    const float* fc1     = (const float*)d_in[2];   // [D, 3D]
    const float* fc2     = (const float*)d_in[3];   // [1, D]
    const float* loopw   = (const float*)d_in[4];   // [D, D]
    const int*   esrc    = (const int*)d_in[5];
    const int*   edst    = (const int*)d_in[6];
    const int*   etyp    = (const int*)d_in[7];
    float* out = (float*)d_out;
    float* ws  = (float*)d_ws;

    float*    w       = ws + OFF_W;
    float*    s1      = ws + OFF_S1;
    float*    s2      = ws + OFF_S2;
    float*    s3      = ws + OFF_S3;
    int*      counts  = (int*)(ws + OFF_COUNTS);
    int*      offsets = (int*)(ws + OFF_OFFSETS);
    int*      bsums   = (int*)(ws + OFF_BSUMS);
    int*      rank    = (int*)(ws + OFF_RANK);
    unsigned* pairs   = (unsigned*)(ws + OFF_PAIRS);
    u16*      hb      = (u16*)(ws + OFF_HB);
    u16*      wt      = (u16*)(ws + OFF_WT);

    // 1: w + Wt^T bf16 + zero counts
    k_prep<<<1 + 64 + ZERO_BLOCKS, 256, 0, stream>>>(fc1, fc2, loopw, w, wt, counts);

    // 2: node scores + bf16 cast + edge histogram (saving per-edge rank)
    k_scores_cast_count<<<SCORE_BLOCKS + CNT_BLOCKS, 256, 0, stream>>>(
        h, emb_rel, w, s1, s2, s3, hb, edst, counts, rank);

    // 3,4: two-level scan (base-add folded into consumers)
    k_scan1<<<ZERO_BLOCKS, 256, 0, stream>>>(counts, offsets, bsums);
    k_scan2<<<1, 256, 0, stream>>>(bsums, ZERO_BLOCKS);

    // 5: atomic-free CSR fill overlapped with MFMA self-loop GEMM
    k_scatter_gemm<<<EDGE_BLOCKS + GEMM_BLOCKS, 256, 0, stream>>>(
        esrc, edst, etyp, rank, s1, s2, s3, offsets, bsums, pairs, hb, wt, out);

    // 6: softmax-normalized weighted gather (RMW out)
    k_gather<<<(N_NODES * 16 + 255) / 256, 256, 0, stream>>>(hb, offsets, bsums, pairs, out);
}